// Round 14
// baseline (348.938 us; speedup 1.0000x reference)
//
#include <hip/hip_runtime.h>

#define NN 50000
#define DIM 256
#define HH 8
#define TT 2
#define EE 800000
#define HDIM 32

#define NPART 98        // buckets per t, 512 nodes each
#define RNODE 512
#define BCAP 12288      // bucket capacity (mean 8192, +45 sigma)
#define K1CH 8192       // edges per edge_bucket_k block
#define K1BLK 98        // ceil(EE / K1CH)

typedef __attribute__((ext_vector_type(8))) short short8;
typedef __attribute__((ext_vector_type(8))) unsigned short ushort8v;
typedef __attribute__((ext_vector_type(4))) unsigned short u16x4;
typedef __attribute__((ext_vector_type(4))) float f32x4;
typedef __attribute__((ext_vector_type(2))) float f32x2;
typedef __attribute__((ext_vector_type(4))) unsigned int u32x4;
typedef __attribute__((ext_vector_type(2))) unsigned int u32x2;

typedef __attribute__((address_space(3))) unsigned int u32_lds;
typedef __attribute__((address_space(1))) const unsigned int u32_glb;

__device__ __forceinline__ float bf2f(ushort u) {
    return __uint_as_float(((unsigned)u) << 16);
}
__device__ __forceinline__ ushort f2bf(float f) {
    unsigned u = __float_as_uint(f);
    unsigned r = u + 0x7fffu + ((u >> 16) & 1u);
    return (ushort)(r >> 16);
}

// fp8 e4m3 packed decode (HW): bytes [0:1] (HI=false) or [2:3] (HI=true) of w
template <bool HI>
__device__ __forceinline__ f32x2 cvtpk8(unsigned w) {
    return __builtin_amdgcn_cvt_pk_f32_fp8((int)w, HI);
}

// ---------- fused convert: x -> bf16 xb AND out[:, 0:256] (NT stores) ----------
__global__ void cvt_xout_k(const float* __restrict__ x, ushort* __restrict__ xb,
                           float* __restrict__ out) {
    int i = blockIdx.x * blockDim.x + threadIdx.x;
    if (i < NN * 64) {
        int n = i >> 6;
        int c = i & 63;
        f32x4 v = ((const f32x4*)x)[i];
        u16x4 o;
        o[0] = f2bf(v[0]); o[1] = f2bf(v[1]); o[2] = f2bf(v[2]); o[3] = f2bf(v[3]);
        __builtin_nontemporal_store(o, (u16x4*)xb + i);
        __builtin_nontemporal_store(v, (f32x4*)(out + (size_t)n * 768 + c * 4));
    }
}

// all weights transposed/converted in one launch
__global__ void cvt_w_k(const float* __restrict__ Wqkv, const float* __restrict__ Wout,
                        ushort* __restrict__ wqkvt, ushort* __restrict__ woutt) {
    int idx = blockIdx.x * blockDim.x + threadIdx.x;
    if (idx < 256 * 1536) {
        int k = idx / 1536;
        int nn = idx - k * 1536;
        wqkvt[nn * 256 + k] = f2bf(Wqkv[idx]);
    } else {
        int j = idx - 256 * 1536;
        if (j < TT * 65536) {
            int t = j >> 16;
            int r = j & 65535;
            int k = r >> 8;
            int nn = r & 255;
            woutt[t * 65536 + nn * 256 + k] = f2bf(Wout[t * 65536 + k * 256 + nn]);
        }
    }
}

// ---------- m97-style MFMA GEMM: 128x128 tile, BK=64, global_load_lds + XOR swizzle ----
// 1-D flat grid + bijective XCD swizzle (T1, m204).
template <int EPI>
__global__ __launch_bounds__(256) void gemm3_k(
    const ushort* __restrict__ A, const ushort* __restrict__ Bt,
    const float* __restrict__ bias,
    ushort* __restrict__ qo, unsigned char* __restrict__ kvo,
    float* __restrict__ outf, int M)
{
    __shared__ ushort As[128 * 64];
    __shared__ ushort Bs[128 * 64];
    const int tid = threadIdx.x;
    const int lane = tid & 63;
    const int w = tid >> 6;          // 4 waves: 2M x 2N
    const int wr = w >> 1, wc = w & 1;
    const int lr = lane & 15;
    const int lq = lane >> 4;

    constexpr int NY = (EPI == 0) ? 12 : 4;
    constexpr int NWG = 391 * NY;
    constexpr int qq = NWG / 8, rr8 = NWG % 8;
    int flat = blockIdx.x;
    int xcd = flat & 7;
    int idx = flat >> 3;
    int wgid = (xcd < rr8 ? xcd * (qq + 1) : rr8 * (qq + 1) + (xcd - rr8) * qq) + idx;
    int bx = wgid / NY;
    int by = wgid - bx * NY;
    const int m0 = bx * 128;

    int n0, col_base = 0, tsel = 0;
    if (EPI == 0) {
        n0 = by * 128;
    } else {
        tsel = by >> 1;
        n0 = (by & 1) * 128;
        col_base = 256 + tsel * 256;
    }
    const ushort* A_  = (EPI == 0) ? A  : A  + (size_t)tsel * NN * 256;
    const ushort* Bt_ = (EPI == 0) ? Bt : Bt + (size_t)tsel * 65536;
    const float* bias_ = (EPI == 0) ? bias : bias + tsel * 256;

    f32x4 acc[4][4];
#pragma unroll
    for (int mt = 0; mt < 4; ++mt)
#pragma unroll
        for (int nt = 0; nt < 4; ++nt) acc[mt][nt] = (f32x4){0.f, 0.f, 0.f, 0.f};

    for (int ks = 0; ks < 256; ks += 64) {
#pragma unroll
        for (int it = 0; it < 4; ++it) {
            int u = tid + it * 256;          // 0..1023: row=u>>3, slot=u&7
            int r = u >> 3, s = u & 7;
            int ss = (s ^ (r & 7)) << 3;     // pre-swizzled source slot (elements)
            const ushort* srcA = A_ + (size_t)(m0 + r) * 256 + ks + ss;
            __builtin_amdgcn_global_load_lds((u32_glb*)srcA,
                (u32_lds*)((char*)As + (u << 4)), 16, 0, 0);
            const ushort* srcB = Bt_ + (size_t)(n0 + r) * 256 + ks + ss;
            __builtin_amdgcn_global_load_lds((u32_glb*)srcB,
                (u32_lds*)((char*)Bs + (u << 4)), 16, 0, 0);
        }
        __syncthreads();

#pragma unroll
        for (int ku = 0; ku < 2; ++ku) {
            short8 a[4], b[4];
#pragma unroll
            for (int mt = 0; mt < 4; ++mt) {
                int row = wr * 64 + mt * 16 + lr;
                int s = ku * 4 + lq;
                a[mt] = *(const short8*)((const char*)As + row * 128 + (((s ^ (row & 7)) & 7) << 4));
            }
#pragma unroll
            for (int nt = 0; nt < 4; ++nt) {
                int row = wc * 64 + nt * 16 + lr;
                int s = ku * 4 + lq;
                b[nt] = *(const short8*)((const char*)Bs + row * 128 + (((s ^ (row & 7)) & 7) << 4));
            }
#pragma unroll
            for (int mt = 0; mt < 4; ++mt)
#pragma unroll
                for (int nt = 0; nt < 4; ++nt)
                    acc[mt][nt] = __builtin_amdgcn_mfma_f32_16x16x32_bf16(a[mt], b[nt], acc[mt][nt], 0, 0, 0);
        }
        __syncthreads();
    }

#pragma unroll
    for (int mt = 0; mt < 4; ++mt) {
        int rowb = m0 + wr * 64 + mt * 16 + (lq << 2);
#pragma unroll
        for (int nt = 0; nt < 4; ++nt) {
            int col = n0 + wc * 64 + nt * 16 + lr;
            float bv = bias_[col];
#pragma unroll
            for (int r2 = 0; r2 < 4; ++r2) {
                int rr = rowb + r2;
                if (rr < M) {
                    float val = acc[mt][nt][r2] + bv;
                    if (EPI == 0) {
                        int t = col / 768;
                        int rem = col - t * 768;
                        int h = rem / 96;
                        int rem2 = rem - h * 96;
                        int s3 = rem2 >> 5;
                        int hd = rem2 & 31;
                        int d = h * 32 + hd;
                        if (s3 == 0) {
                            qo[((size_t)(t * NN + rr)) * 256 + d] = f2bf(val);
                        } else {
                            unsigned by8 = ((unsigned)__builtin_amdgcn_cvt_pk_fp8_f32(val, val, 0, false)) & 0xffu;
                            size_t off = ((size_t)(t * NN + rr)) * 512 +
                                         ((size_t)(d >> 3) << 4) + (d & 7) + ((s3 == 2) ? 8 : 0);
                            kvo[off] = (unsigned char)by8;
                        }
                    } else {
                        __builtin_nontemporal_store(val, outf + (size_t)rr * 768 + col_base + col);
                    }
                }
            }
        }
    }
}

// ---------- bucket-partition CSR build ----------
__global__ __launch_bounds__(256) void edge_bucket_k(
    const int* __restrict__ dst, const int* __restrict__ src,
    int* __restrict__ bcursor, unsigned long long* __restrict__ bpair)
{
    int t = blockIdx.x / K1BLK;
    int cb = blockIdx.x - t * K1BLK;
    int base = cb * K1CH;
    const int* dp = dst + (size_t)t * EE;
    const int* sp = src + (size_t)t * EE;
    __shared__ int bcnt[NPART];
    __shared__ int bbase_l[NPART];
    int tid = threadIdx.x;
    if (tid < NPART) bcnt[tid] = 0;
    __syncthreads();
    int lim = EE - base; if (lim > K1CH) lim = K1CH;
#pragma unroll
    for (int it = 0; it < K1CH / 1024; ++it) {
        int i = (it * 256 + tid) * 4;
        if (i < lim) {
            int4 d4 = *(const int4*)(dp + base + i);
            atomicAdd(&bcnt[d4.x >> 9], 1);
            atomicAdd(&bcnt[d4.y >> 9], 1);
            atomicAdd(&bcnt[d4.z >> 9], 1);
            atomicAdd(&bcnt[d4.w >> 9], 1);
        }
    }
    __syncthreads();
    if (tid < NPART)
        bbase_l[tid] = atomicAdd(&bcursor[t * NPART + tid], bcnt[tid]);
    __syncthreads();
    if (tid < NPART) bcnt[tid] = 0;   // reuse as local cursor
    __syncthreads();
#pragma unroll
    for (int it = 0; it < K1CH / 1024; ++it) {
        int i = (it * 256 + tid) * 4;
        if (i < lim) {
            int4 d4 = *(const int4*)(dp + base + i);
            int4 s4 = *(const int4*)(sp + base + i);
            int dd[4] = {d4.x, d4.y, d4.z, d4.w};
            int ss[4] = {s4.x, s4.y, s4.z, s4.w};
#pragma unroll
            for (int e = 0; e < 4; ++e) {
                int p = dd[e] >> 9;
                int pos = bbase_l[p] + atomicAdd(&bcnt[p], 1);
                if (pos < BCAP) {
                    unsigned long long pr = (unsigned)ss[e] |
                        ((unsigned long long)(unsigned)dd[e] << 32);
                    __builtin_nontemporal_store(pr,
                        bpair + (size_t)(t * NPART + p) * BCAP + pos);
                }
            }
        }
    }
}

// per-bucket: self-computed prefix over bcursor, LDS hist(512) -> scan -> offs,
// LDS-staged placement -> coalesced srt segment write.
__global__ __launch_bounds__(512) void bucket_scatter_k(
    const unsigned long long* __restrict__ bpair, const int* __restrict__ bcursor,
    int* __restrict__ offs, int* __restrict__ srt)
{
    int b = blockIdx.x;              // 0..TT*NPART-1
    int t = b / NPART, p = b - t * NPART;
    int lo = p * RNODE;
    __shared__ int cnts[NPART];
    __shared__ int hist[RNODE];
    __shared__ int scn[RNODE];
    __shared__ int stage[BCAP];
    int tid = threadIdx.x;
    if (tid < NPART) cnts[tid] = bcursor[t * NPART + tid];
    hist[tid] = 0;
    __syncthreads();
    int n = cnts[p]; if (n > BCAP) n = BCAP;
    int gbase = 0;
    for (int i = 0; i < p; ++i) gbase += cnts[i];   // LDS broadcast, <=97 iters
    const unsigned long long* ep = bpair + (size_t)b * BCAP;
    for (int i = tid; i < n; i += 512)
        atomicAdd(&hist[(int)(ep[i] >> 32) - lo], 1);
    __syncthreads();
    scn[tid] = hist[tid];
    __syncthreads();
    for (int off = 1; off < RNODE; off <<= 1) {
        int v = (tid >= off) ? scn[tid - off] : 0;
        __syncthreads();
        scn[tid] += v;
        __syncthreads();
    }
    int ex = scn[tid] - hist[tid];
    int node = lo + tid;
    if (node < NN) offs[t * (NN + 1) + node] = gbase + ex;
    if (p == NPART - 1 && tid == 0) offs[t * (NN + 1) + NN] = EE;
    hist[tid] = ex;                  // reuse as per-node cursor
    __syncthreads();
    for (int i = tid; i < n; i += 512) {
        unsigned long long e = ep[i];
        int pos = atomicAdd(&hist[(int)(e >> 32) - lo], 1);
        stage[pos] = (int)(unsigned)e;
    }
    __syncthreads();
    int* so = srt + (size_t)t * EE + gbase;
    for (int i = tid; i < n; i += 512)
        __builtin_nontemporal_store(stage[i], so + i);
}

// ---------- fused edge attention (scalar decode, unroll 4) ----------
__device__ __forceinline__ float f8dot(u32x4 kv, const float* q)
{
    f32x2 c0 = cvtpk8<false>(kv[0]);
    f32x2 c1 = cvtpk8<true>(kv[0]);
    f32x2 c2 = cvtpk8<false>(kv[1]);
    f32x2 c3 = cvtpk8<true>(kv[1]);
    return q[0] * c0[0] + q[1] * c0[1] + q[2] * c1[0] + q[3] * c1[1] +
           q[4] * c2[0] + q[5] * c2[1] + q[6] * c3[0] + q[7] * c3[1];
}

__device__ __forceinline__ void f8acc(float p, u32x4 kv, float* a)
{
    f32x2 c0 = cvtpk8<false>(kv[2]);
    f32x2 c1 = cvtpk8<true>(kv[2]);
    f32x2 c2 = cvtpk8<false>(kv[3]);
    f32x2 c3 = cvtpk8<true>(kv[3]);
    a[0] += p * c0[0]; a[1] += p * c0[1];
    a[2] += p * c1[0]; a[3] += p * c1[1];
    a[4] += p * c2[0]; a[5] += p * c2[1];
    a[6] += p * c3[0]; a[7] += p * c3[1];
}

__global__ __launch_bounds__(256) void attn_k(
    const ushort* __restrict__ q_ws, const unsigned char* __restrict__ kv_ws,
    const int* __restrict__ offs, const int* __restrict__ srt,
    ushort* __restrict__ agg)
{
    int wid = blockIdx.x * 4 + (threadIdx.x >> 6);
    int lane = threadIdx.x & 63;
    int half = lane >> 5;
    int sub = lane & 31;
    int t = wid / NN;
    int node = wid - t * NN;

    const ushort* qp = q_ws + ((size_t)(t * NN + node)) * 256 + sub * 8;
    ushort8v qu = *(const ushort8v*)qp;
    float q[8];
#pragma unroll
    for (int i = 0; i < 8; ++i) q[i] = bf2f(qu[i]);

    int o0 = offs[t * (NN + 1) + node];
    int o1 = offs[t * (NN + 1) + node + 1];
    const int* sp = srt + (size_t)t * EE;
    const unsigned char* kvb = kv_ws + (size_t)t * NN * 512 + sub * 16;

    const float scale = 0.17677669529663689f;
    float zA = 0.f, zB = 0.f;
    float aA[8] = {0.f, 0.f, 0.f, 0.f, 0.f, 0.f, 0.f, 0.f};
    float aB[8] = {0.f, 0.f, 0.f, 0.f, 0.f, 0.f, 0.f, 0.f};

    int j = o0;
    for (; j + 4 <= o1; j += 4) {
        int s0 = sp[j + half];
        int s1 = sp[j + 2 + half];
        u32x4 kv0 = *(const u32x4*)(kvb + (size_t)s0 * 512);
        u32x4 kv1 = *(const u32x4*)(kvb + (size_t)s1 * 512);
        float d0 = f8dot(kv0, q);
        float d1 = f8dot(kv1, q);
        d0 += __shfl_xor(d0, 1); d1 += __shfl_xor(d1, 1);
        d0 += __shfl_xor(d0, 2); d1 += __shfl_xor(d1, 2);
        float p0 = __expf(d0 * scale);
        float p1 = __expf(d1 * scale);
        zA += p0; zB += p1;
        f8acc(p0, kv0, aA);
        f8acc(p1, kv1, aB);
    }
    for (; j < o1; j += 2) {
        int e = j + half;
        int valid = (e < o1) ? 1 : 0;
        int s0 = sp[valid ? e : j];
        u32x4 kv0 = *(const u32x4*)(kvb + (size_t)s0 * 512);
        float d0 = f8dot(kv0, q);
        d0 += __shfl_xor(d0, 1);
        d0 += __shfl_xor(d0, 2);
        float p0 = valid ? __expf(d0 * scale) : 0.f;
        zA += p0;
        f8acc(p0, kv0, aA);
    }

    float z = zA + zB;
    z += __shfl_xor(z, 32);
    float a[8];
#pragma unroll
    for (int i = 0; i < 8; ++i) {
        a[i] = aA[i] + aB[i];
        a[i] += __shfl_xor(a[i], 32);
    }

    if (half == 0) {
        float inv = (z > 0.f) ? 1.0f / z : 0.f;
        ushort8v r;
#pragma unroll
        for (int i = 0; i < 8; ++i) r[i] = f2bf(a[i] * inv);
        *(ushort8v*)(agg + ((size_t)(t * NN + node)) * 256 + sub * 8) = r;
    }
}

extern "C" void kernel_launch(void* const* d_in, const int* in_sizes, int n_in,
                              void* d_out, int out_size, void* d_ws, size_t ws_size,
                              hipStream_t stream)
{
    const float* x      = (const float*)d_in[0];
    const float* W_qkv  = (const float*)d_in[1];
    const float* b_qkv  = (const float*)d_in[2];
    const float* W_out  = (const float*)d_in[3];
    const float* b_out  = (const float*)d_in[4];
    const int* edge_src = (const int*)d_in[5];
    const int* edge_dst = (const int*)d_in[6];
    float* out = (float*)d_out;

    char* ws = (char*)d_ws;
    size_t off = 0;
    auto carve = [&](size_t bytes) {
        char* p = ws + off;
        off += (bytes + 255) & ~(size_t)255;
        return p;
    };
    ushort* xb    = (ushort*)carve((size_t)NN * DIM * 2);
    ushort* wqkvt = (ushort*)carve((size_t)1536 * 256 * 2);
    ushort* woutt = (ushort*)carve((size_t)TT * 256 * 256 * 2);
    ushort* q_ws  = (ushort*)carve((size_t)TT * NN * 256 * 2);
    unsigned char* kv_ws = (unsigned char*)carve((size_t)TT * NN * 512);
    ushort* aggb  = (ushort*)carve((size_t)TT * NN * 256 * 2);
    int* offs     = (int*)carve((size_t)TT * (NN + 1) * 4);
    int* srt      = (int*)carve((size_t)TT * EE * 4);
    unsigned long long* bpair = (unsigned long long*)carve((size_t)TT * NPART * BCAP * 8);
    int* bcursor  = (int*)carve((size_t)TT * NPART * 4);

    (void)hipMemsetAsync(bcursor, 0, (size_t)TT * NPART * 4, stream);

    cvt_xout_k<<<(NN * 64 + 255) / 256, 256, 0, stream>>>(x, xb, out);
    cvt_w_k<<<(256 * 1536 + TT * 65536 + 255) / 256, 256, 0, stream>>>(W_qkv, W_out,
                                                                       wqkvt, woutt);

    gemm3_k<0><<<391 * 12, 256, 0, stream>>>(xb, wqkvt, b_qkv, q_ws, kv_ws,
                                             nullptr, NN);

    edge_bucket_k<<<TT * K1BLK, 256, 0, stream>>>(edge_dst, edge_src, bcursor, bpair);
    bucket_scatter_k<<<TT * NPART, 512, 0, stream>>>(bpair, bcursor, offs, srt);

    attn_k<<<(NN * TT) / 4, 256, 0, stream>>>(q_ws, kv_ws, offs, srt, aggb);

    gemm3_k<1><<<391 * 4, 256, 0, stream>>>(aggb, woutt, b_out,
                                            nullptr, nullptr, out, NN);
}

// Round 15
// 316.357 us; speedup vs baseline: 1.1030x; 1.1030x over previous
//
#include <hip/hip_runtime.h>

#define NN 50000
#define DIM 256
#define HH 8
#define TT 2
#define EE 800000
#define HDIM 32

#define NPART 98        // buckets per t, 512 nodes each
#define RNODE 512
#define BCAP 12288      // bucket capacity (mean 8192, +45 sigma)
#define K1CH 8192       // edges per edge_bucket_k block
#define K1BLK 98        // ceil(EE / K1CH)

typedef __attribute__((ext_vector_type(8))) short short8;
typedef __attribute__((ext_vector_type(8))) unsigned short ushort8v;
typedef __attribute__((ext_vector_type(4))) unsigned short u16x4;
typedef __attribute__((ext_vector_type(4))) float f32x4;
typedef __attribute__((ext_vector_type(2))) float f32x2;
typedef __attribute__((ext_vector_type(4))) unsigned int u32x4;

typedef __attribute__((address_space(3))) unsigned int u32_lds;
typedef __attribute__((address_space(1))) const unsigned int u32_glb;

__device__ __forceinline__ float bf2f(ushort u) {
    return __uint_as_float(((unsigned)u) << 16);
}
__device__ __forceinline__ ushort f2bf(float f) {
    unsigned u = __float_as_uint(f);
    unsigned r = u + 0x7fffu + ((u >> 16) & 1u);
    return (ushort)(r >> 16);
}

// fp8 e4m3 packed decode (HW): bytes [0:1] (HI=false) or [2:3] (HI=true) of w
template <bool HI>
__device__ __forceinline__ f32x2 cvtpk8(unsigned w) {
    return __builtin_amdgcn_cvt_pk_f32_fp8((int)w, HI);
}

// ---------- fused convert: x -> bf16 xb (cached) AND out[:, 0:256] (NT) ----------
__global__ void cvt_xout_k(const float* __restrict__ x, ushort* __restrict__ xb,
                           float* __restrict__ out) {
    int i = blockIdx.x * blockDim.x + threadIdx.x;
    if (i < NN * 64) {
        int n = i >> 6;
        int c = i & 63;
        f32x4 v = ((const f32x4*)x)[i];
        u16x4 o;
        o[0] = f2bf(v[0]); o[1] = f2bf(v[1]); o[2] = f2bf(v[2]); o[3] = f2bf(v[3]);
        ((u16x4*)xb)[i] = o;                       // consumed by gemm<0>: keep cached
        __builtin_nontemporal_store(v, (f32x4*)(out + (size_t)n * 768 + c * 4));
    }
}

// all weights transposed/converted in one launch
__global__ void cvt_w_k(const float* __restrict__ Wqkv, const float* __restrict__ Wout,
                        ushort* __restrict__ wqkvt, ushort* __restrict__ woutt) {
    int idx = blockIdx.x * blockDim.x + threadIdx.x;
    if (idx < 256 * 1536) {
        int k = idx / 1536;
        int nn = idx - k * 1536;
        wqkvt[nn * 256 + k] = f2bf(Wqkv[idx]);
    } else {
        int j = idx - 256 * 1536;
        if (j < TT * 65536) {
            int t = j >> 16;
            int r = j & 65535;
            int k = r >> 8;
            int nn = r & 255;
            woutt[t * 65536 + nn * 256 + k] = f2bf(Wout[t * 65536 + k * 256 + nn]);
        }
    }
}

// ---------- m97-style MFMA GEMM: 128x128 tile, BK=64, global_load_lds + XOR swizzle ----
// 1-D flat grid + bijective XCD swizzle (T1, m204).
template <int EPI>
__global__ __launch_bounds__(256) void gemm3_k(
    const ushort* __restrict__ A, const ushort* __restrict__ Bt,
    const float* __restrict__ bias,
    ushort* __restrict__ qo, unsigned char* __restrict__ kvo,
    float* __restrict__ outf, int M)
{
    __shared__ ushort As[128 * 64];
    __shared__ ushort Bs[128 * 64];
    const int tid = threadIdx.x;
    const int lane = tid & 63;
    const int w = tid >> 6;          // 4 waves: 2M x 2N
    const int wr = w >> 1, wc = w & 1;
    const int lr = lane & 15;
    const int lq = lane >> 4;

    constexpr int NY = (EPI == 0) ? 12 : 4;
    constexpr int NWG = 391 * NY;
    constexpr int qq = NWG / 8, rr8 = NWG % 8;
    int flat = blockIdx.x;
    int xcd = flat & 7;
    int idx = flat >> 3;
    int wgid = (xcd < rr8 ? xcd * (qq + 1) : rr8 * (qq + 1) + (xcd - rr8) * qq) + idx;
    int bx = wgid / NY;
    int by = wgid - bx * NY;
    const int m0 = bx * 128;

    int n0, col_base = 0, tsel = 0;
    if (EPI == 0) {
        n0 = by * 128;
    } else {
        tsel = by >> 1;
        n0 = (by & 1) * 128;
        col_base = 256 + tsel * 256;
    }
    const ushort* A_  = (EPI == 0) ? A  : A  + (size_t)tsel * NN * 256;
    const ushort* Bt_ = (EPI == 0) ? Bt : Bt + (size_t)tsel * 65536;
    const float* bias_ = (EPI == 0) ? bias : bias + tsel * 256;

    f32x4 acc[4][4];
#pragma unroll
    for (int mt = 0; mt < 4; ++mt)
#pragma unroll
        for (int nt = 0; nt < 4; ++nt) acc[mt][nt] = (f32x4){0.f, 0.f, 0.f, 0.f};

    for (int ks = 0; ks < 256; ks += 64) {
#pragma unroll
        for (int it = 0; it < 4; ++it) {
            int u = tid + it * 256;          // 0..1023: row=u>>3, slot=u&7
            int r = u >> 3, s = u & 7;
            int ss = (s ^ (r & 7)) << 3;     // pre-swizzled source slot (elements)
            const ushort* srcA = A_ + (size_t)(m0 + r) * 256 + ks + ss;
            __builtin_amdgcn_global_load_lds((u32_glb*)srcA,
                (u32_lds*)((char*)As + (u << 4)), 16, 0, 0);
            const ushort* srcB = Bt_ + (size_t)(n0 + r) * 256 + ks + ss;
            __builtin_amdgcn_global_load_lds((u32_glb*)srcB,
                (u32_lds*)((char*)Bs + (u << 4)), 16, 0, 0);
        }
        __syncthreads();

#pragma unroll
        for (int ku = 0; ku < 2; ++ku) {
            short8 a[4], b[4];
#pragma unroll
            for (int mt = 0; mt < 4; ++mt) {
                int row = wr * 64 + mt * 16 + lr;
                int s = ku * 4 + lq;
                a[mt] = *(const short8*)((const char*)As + row * 128 + (((s ^ (row & 7)) & 7) << 4));
            }
#pragma unroll
            for (int nt = 0; nt < 4; ++nt) {
                int row = wc * 64 + nt * 16 + lr;
                int s = ku * 4 + lq;
                b[nt] = *(const short8*)((const char*)Bs + row * 128 + (((s ^ (row & 7)) & 7) << 4));
            }
#pragma unroll
            for (int mt = 0; mt < 4; ++mt)
#pragma unroll
                for (int nt = 0; nt < 4; ++nt)
                    acc[mt][nt] = __builtin_amdgcn_mfma_f32_16x16x32_bf16(a[mt], b[nt], acc[mt][nt], 0, 0, 0);
        }
        __syncthreads();
    }

#pragma unroll
    for (int mt = 0; mt < 4; ++mt) {
        int rowb = m0 + wr * 64 + mt * 16 + (lq << 2);
#pragma unroll
        for (int nt = 0; nt < 4; ++nt) {
            int col = n0 + wc * 64 + nt * 16 + lr;
            float bv = bias_[col];
#pragma unroll
            for (int r2 = 0; r2 < 4; ++r2) {
                int rr = rowb + r2;
                if (rr < M) {
                    float val = acc[mt][nt][r2] + bv;
                    if (EPI == 0) {
                        int t = col / 768;
                        int rem = col - t * 768;
                        int h = rem / 96;
                        int rem2 = rem - h * 96;
                        int s3 = rem2 >> 5;
                        int hd = rem2 & 31;
                        int d = h * 32 + hd;
                        if (s3 == 0) {
                            qo[((size_t)(t * NN + rr)) * 256 + d] = f2bf(val);
                        } else {
                            unsigned by8 = ((unsigned)__builtin_amdgcn_cvt_pk_fp8_f32(val, val, 0, false)) & 0xffu;
                            size_t off = ((size_t)(t * NN + rr)) * 512 +
                                         ((size_t)(d >> 3) << 4) + (d & 7) + ((s3 == 2) ? 8 : 0);
                            kvo[off] = (unsigned char)by8;
                        }
                    } else {
                        __builtin_nontemporal_store(val, outf + (size_t)rr * 768 + col_base + col);
                    }
                }
            }
        }
    }
}

// ---------- bucket-partition CSR build ----------
__global__ __launch_bounds__(256) void edge_bucket_k(
    const int* __restrict__ dst, const int* __restrict__ src,
    int* __restrict__ bcursor, unsigned long long* __restrict__ bpair)
{
    int t = blockIdx.x / K1BLK;
    int cb = blockIdx.x - t * K1BLK;
    int base = cb * K1CH;
    const int* dp = dst + (size_t)t * EE;
    const int* sp = src + (size_t)t * EE;
    __shared__ int bcnt[NPART];
    __shared__ int bbase_l[NPART];
    int tid = threadIdx.x;
    if (tid < NPART) bcnt[tid] = 0;
    __syncthreads();
    int lim = EE - base; if (lim > K1CH) lim = K1CH;
#pragma unroll
    for (int it = 0; it < K1CH / 1024; ++it) {
        int i = (it * 256 + tid) * 4;
        if (i < lim) {
            int4 d4 = *(const int4*)(dp + base + i);
            atomicAdd(&bcnt[d4.x >> 9], 1);
            atomicAdd(&bcnt[d4.y >> 9], 1);
            atomicAdd(&bcnt[d4.z >> 9], 1);
            atomicAdd(&bcnt[d4.w >> 9], 1);
        }
    }
    __syncthreads();
    if (tid < NPART)
        bbase_l[tid] = atomicAdd(&bcursor[t * NPART + tid], bcnt[tid]);
    __syncthreads();
    if (tid < NPART) bcnt[tid] = 0;   // reuse as local cursor
    __syncthreads();
#pragma unroll
    for (int it = 0; it < K1CH / 1024; ++it) {
        int i = (it * 256 + tid) * 4;
        if (i < lim) {
            int4 d4 = *(const int4*)(dp + base + i);
            int4 s4 = *(const int4*)(sp + base + i);
            int dd[4] = {d4.x, d4.y, d4.z, d4.w};
            int ss[4] = {s4.x, s4.y, s4.z, s4.w};
#pragma unroll
            for (int e = 0; e < 4; ++e) {
                int p = dd[e] >> 9;
                int pos = bbase_l[p] + atomicAdd(&bcnt[p], 1);
                if (pos < BCAP)
                    bpair[(size_t)(t * NPART + p) * BCAP + pos] =
                        (unsigned)ss[e] | ((unsigned long long)(unsigned)dd[e] << 32);
            }
        }
    }
}

// per-bucket: self-computed prefix over bcursor, LDS hist(512) -> scan -> offs,
// LDS-staged placement -> coalesced srt segment write.
__global__ __launch_bounds__(512) void bucket_scatter_k(
    const unsigned long long* __restrict__ bpair, const int* __restrict__ bcursor,
    int* __restrict__ offs, int* __restrict__ srt)
{
    int b = blockIdx.x;              // 0..TT*NPART-1
    int t = b / NPART, p = b - t * NPART;
    int lo = p * RNODE;
    __shared__ int cnts[NPART];
    __shared__ int hist[RNODE];
    __shared__ int scn[RNODE];
    __shared__ int stage[BCAP];
    int tid = threadIdx.x;
    if (tid < NPART) cnts[tid] = bcursor[t * NPART + tid];
    hist[tid] = 0;
    __syncthreads();
    int n = cnts[p]; if (n > BCAP) n = BCAP;
    int gbase = 0;
    for (int i = 0; i < p; ++i) gbase += cnts[i];   // LDS broadcast, <=97 iters
    const unsigned long long* ep = bpair + (size_t)b * BCAP;
    for (int i = tid; i < n; i += 512)
        atomicAdd(&hist[(int)(ep[i] >> 32) - lo], 1);
    __syncthreads();
    scn[tid] = hist[tid];
    __syncthreads();
    for (int off = 1; off < RNODE; off <<= 1) {
        int v = (tid >= off) ? scn[tid - off] : 0;
        __syncthreads();
        scn[tid] += v;
        __syncthreads();
    }
    int ex = scn[tid] - hist[tid];
    int node = lo + tid;
    if (node < NN) offs[t * (NN + 1) + node] = gbase + ex;
    if (p == NPART - 1 && tid == 0) offs[t * (NN + 1) + NN] = EE;
    hist[tid] = ex;                  // reuse as per-node cursor
    __syncthreads();
    for (int i = tid; i < n; i += 512) {
        unsigned long long e = ep[i];
        int pos = atomicAdd(&hist[(int)(e >> 32) - lo], 1);
        stage[pos] = (int)(unsigned)e;
    }
    __syncthreads();
    int* so = srt + (size_t)t * EE + gbase;
    for (int i = tid; i < n; i += 512) so[i] = stage[i];
}

// ---------- fused edge attention (scalar decode, unroll 4) ----------
__device__ __forceinline__ float f8dot(u32x4 kv, const float* q)
{
    f32x2 c0 = cvtpk8<false>(kv[0]);
    f32x2 c1 = cvtpk8<true>(kv[0]);
    f32x2 c2 = cvtpk8<false>(kv[1]);
    f32x2 c3 = cvtpk8<true>(kv[1]);
    return q[0] * c0[0] + q[1] * c0[1] + q[2] * c1[0] + q[3] * c1[1] +
           q[4] * c2[0] + q[5] * c2[1] + q[6] * c3[0] + q[7] * c3[1];
}

__device__ __forceinline__ void f8acc(float p, u32x4 kv, float* a)
{
    f32x2 c0 = cvtpk8<false>(kv[2]);
    f32x2 c1 = cvtpk8<true>(kv[2]);
    f32x2 c2 = cvtpk8<false>(kv[3]);
    f32x2 c3 = cvtpk8<true>(kv[3]);
    a[0] += p * c0[0]; a[1] += p * c0[1];
    a[2] += p * c1[0]; a[3] += p * c1[1];
    a[4] += p * c2[0]; a[5] += p * c2[1];
    a[6] += p * c3[0]; a[7] += p * c3[1];
}

__global__ __launch_bounds__(256) void attn_k(
    const ushort* __restrict__ q_ws, const unsigned char* __restrict__ kv_ws,
    const int* __restrict__ offs, const int* __restrict__ srt,
    ushort* __restrict__ agg)
{
    int wid = blockIdx.x * 4 + (threadIdx.x >> 6);
    int lane = threadIdx.x & 63;
    int half = lane >> 5;
    int sub = lane & 31;
    int t = wid / NN;
    int node = wid - t * NN;

    const ushort* qp = q_ws + ((size_t)(t * NN + node)) * 256 + sub * 8;
    ushort8v qu = *(const ushort8v*)qp;
    float q[8];
#pragma unroll
    for (int i = 0; i < 8; ++i) q[i] = bf2f(qu[i]);

    int o0 = offs[t * (NN + 1) + node];
    int o1 = offs[t * (NN + 1) + node + 1];
    const int* sp = srt + (size_t)t * EE;
    const unsigned char* kvb = kv_ws + (size_t)t * NN * 512 + sub * 16;

    const float scale = 0.17677669529663689f;
    float zA = 0.f, zB = 0.f;
    float aA[8] = {0.f, 0.f, 0.f, 0.f, 0.f, 0.f, 0.f, 0.f};
    float aB[8] = {0.f, 0.f, 0.f, 0.f, 0.f, 0.f, 0.f, 0.f};

    int j = o0;
    for (; j + 4 <= o1; j += 4) {
        int s0 = sp[j + half];
        int s1 = sp[j + 2 + half];
        u32x4 kv0 = *(const u32x4*)(kvb + (size_t)s0 * 512);
        u32x4 kv1 = *(const u32x4*)(kvb + (size_t)s1 * 512);
        float d0 = f8dot(kv0, q);
        float d1 = f8dot(kv1, q);
        d0 += __shfl_xor(d0, 1); d1 += __shfl_xor(d1, 1);
        d0 += __shfl_xor(d0, 2); d1 += __shfl_xor(d1, 2);
        float p0 = __expf(d0 * scale);
        float p1 = __expf(d1 * scale);
        zA += p0; zB += p1;
        f8acc(p0, kv0, aA);
        f8acc(p1, kv1, aB);
    }
    for (; j < o1; j += 2) {
        int e = j + half;
        int valid = (e < o1) ? 1 : 0;
        int s0 = sp[valid ? e : j];
        u32x4 kv0 = *(const u32x4*)(kvb + (size_t)s0 * 512);
        float d0 = f8dot(kv0, q);
        d0 += __shfl_xor(d0, 1);
        d0 += __shfl_xor(d0, 2);
        float p0 = valid ? __expf(d0 * scale) : 0.f;
        zA += p0;
        f8acc(p0, kv0, aA);
    }

    float z = zA + zB;
    z += __shfl_xor(z, 32);
    float a[8];
#pragma unroll
    for (int i = 0; i < 8; ++i) {
        a[i] = aA[i] + aB[i];
        a[i] += __shfl_xor(a[i], 32);
    }

    if (half == 0) {
        float inv = (z > 0.f) ? 1.0f / z : 0.f;
        ushort8v r;
#pragma unroll
        for (int i = 0; i < 8; ++i) r[i] = f2bf(a[i] * inv);
        *(ushort8v*)(agg + ((size_t)(t * NN + node)) * 256 + sub * 8) = r;
    }
}

extern "C" void kernel_launch(void* const* d_in, const int* in_sizes, int n_in,
                              void* d_out, int out_size, void* d_ws, size_t ws_size,
                              hipStream_t stream)
{
    const float* x      = (const float*)d_in[0];
    const float* W_qkv  = (const float*)d_in[1];
    const float* b_qkv  = (const float*)d_in[2];
    const float* W_out  = (const float*)d_in[3];
    const float* b_out  = (const float*)d_in[4];
    const int* edge_src = (const int*)d_in[5];
    const int* edge_dst = (const int*)d_in[6];
    float* out = (float*)d_out;

    char* ws = (char*)d_ws;
    size_t off = 0;
    auto carve = [&](size_t bytes) {
        char* p = ws + off;
        off += (bytes + 255) & ~(size_t)255;
        return p;
    };
    ushort* xb    = (ushort*)carve((size_t)NN * DIM * 2);
    ushort* wqkvt = (ushort*)carve((size_t)1536 * 256 * 2);
    ushort* woutt = (ushort*)carve((size_t)TT * 256 * 256 * 2);
    ushort* q_ws  = (ushort*)carve((size_t)TT * NN * 256 * 2);
    unsigned char* kv_ws = (unsigned char*)carve((size_t)TT * NN * 512);
    ushort* aggb  = (ushort*)carve((size_t)TT * NN * 256 * 2);
    int* offs     = (int*)carve((size_t)TT * (NN + 1) * 4);
    int* srt      = (int*)carve((size_t)TT * EE * 4);
    unsigned long long* bpair = (unsigned long long*)carve((size_t)TT * NPART * BCAP * 8);
    int* bcursor  = (int*)carve((size_t)TT * NPART * 4);

    (void)hipMemsetAsync(bcursor, 0, (size_t)TT * NPART * 4, stream);

    cvt_xout_k<<<(NN * 64 + 255) / 256, 256, 0, stream>>>(x, xb, out);
    cvt_w_k<<<(256 * 1536 + TT * 65536 + 255) / 256, 256, 0, stream>>>(W_qkv, W_out,
                                                                       wqkvt, woutt);

    gemm3_k<0><<<391 * 12, 256, 0, stream>>>(xb, wqkvt, b_qkv, q_ws, kv_ws,
                                             nullptr, NN);

    edge_bucket_k<<<TT * K1BLK, 256, 0, stream>>>(edge_dst, edge_src, bcursor, bpair);
    bucket_scatter_k<<<TT * NPART, 512, 0, stream>>>(bpair, bcursor, offs, srt);

    attn_k<<<(NN * TT) / 4, 256, 0, stream>>>(q_ws, kv_ws, offs, srt, aggb);

    gemm3_k<1><<<391 * 4, 256, 0, stream>>>(aggb, woutt, b_out,
                                            nullptr, nullptr, out, NN);
}